// Round 6
// baseline (526.118 us; speedup 1.0000x reference)
//
#include <hip/hip_runtime.h>
#include <hip/hip_bf16.h>
#include <math.h>

// Problem constants (from reference)
#define B_SZ   128
#define HDIM   256
#define NG     1280     // 5*H
#define NNODES 1023
#define VOCAB  2048
#define KS_LVL 24       // K=768 in steps of 32

typedef unsigned int uint32;
typedef short  short8v  __attribute__((ext_vector_type(8)));   // 8 x bf16 (4 VGPR)
typedef float  float4v  __attribute__((ext_vector_type(4)));   // MFMA C/D frag

__device__ __forceinline__ float sigm(float x) {
    return 1.0f / (1.0f + __expf(-x));
}
__device__ __forceinline__ float tanh_fast(float x) {
    return 2.0f / (1.0f + __expf(-2.0f * x)) - 1.0f;
}
__device__ __forceinline__ float bf2f(unsigned short u) {
    return __uint_as_float(((uint32)u) << 16);
}
__device__ __forceinline__ unsigned short f2bf(float f) {
    uint32 x = __float_as_uint(f);
    uint32 r = (x + 0x7FFFu + ((x >> 16) & 1u)) >> 16;   // RNE
    return (unsigned short)r;
}

// ---------------------------------------------------------------------------
// embb = bf16(emb) : 2048 x 256.  1 MB table -> L2-resident gather target.
// ---------------------------------------------------------------------------
__global__ __launch_bounds__(256) void embb_kernel(
    const float* __restrict__ emb, unsigned short* __restrict__ embb)
{
    const int t = blockIdx.x * 256 + threadIdx.x;   // 0..65535, 8 elems each
    const float4 v0 = *(const float4*)(emb + (size_t)t * 8);
    const float4 v1 = *(const float4*)(emb + (size_t)t * 8 + 4);
    short8v o;
    o[0] = (short)f2bf(v0.x); o[1] = (short)f2bf(v0.y);
    o[2] = (short)f2bf(v0.z); o[3] = (short)f2bf(v0.w);
    o[4] = (short)f2bf(v1.x); o[5] = (short)f2bf(v1.y);
    o[6] = (short)f2bf(v1.z); o[7] = (short)f2bf(v1.w);
    *(short8v*)(embb + (size_t)t * 8) = o;
}

// ---------------------------------------------------------------------------
// WTf: fragment-ready bf16 repack of [Ul;Ur;Wx] (K=768, N=1280) for MFMA B.
// short8 index = (ng*24 + ks)*64 + lane ; lane = q*16 + c
//   holds B[k = ks*32 + q*8 + j][col = ng*16 + c],  j = 0..7
// ---------------------------------------------------------------------------
__global__ __launch_bounds__(256) void prep_wtf(
    const float* __restrict__ Ul, const float* __restrict__ Ur,
    const float* __restrict__ Wx, unsigned short* __restrict__ WTf)
{
    const int t = blockIdx.x * 256 + threadIdx.x;   // 0..122879
    const int l = t & 63;
    const int q = l >> 4, c = l & 15;
    const int ks = (t >> 6) % 24;
    const int ng = t / (24 * 64);                    // 0..79
    const int col = ng * 16 + c;
    const int k = ks * 32 + q * 8;
    const float* src = (k < 256) ? (Ul + (size_t)k * NG + col)
                     : (k < 512) ? (Ur + (size_t)(k - 256) * NG + col)
                                 : (Wx + (size_t)(k - 512) * NG + col);
    short8v v;
    #pragma unroll
    for (int j = 0; j < 8; ++j) v[j] = (short)f2bf(src[(size_t)j * NG]);
    *(short8v*)(WTf + (size_t)t * 8) = v;
}

// ---------------------------------------------------------------------------
// Leaf level (d=9): gates {i,o,u} = x @ Wx + b via MFMA, x = embb[tok].
// Row id r = b*512 + i  (h/c layout: row-major by r, 256 cols).
// Block: 4 waves, 64 rows x 64 cols x 3 gates.
// ---------------------------------------------------------------------------
__global__ __launch_bounds__(256) void leaf_kernel(
    const unsigned short* __restrict__ WTf, const unsigned short* __restrict__ embb,
    const float* __restrict__ bias, const int* __restrict__ tokens,
    unsigned short* __restrict__ hdst, unsigned short* __restrict__ cdst)
{
    __shared__ __align__(16) unsigned short wb[2 * 4096];   // 16 KB h/c writeback

    const int tid  = threadIdx.x;
    const int lane = tid & 63;
    const int w    = tid >> 6;
    const int quad = lane >> 4, col15 = lane & 15;
    const int jtile   = blockIdx.x;            // 0..3
    const int rowBase = blockIdx.y * 64;       // 0..65472
    const int jbase   = jtile * 64;

    // A pointers: x rows from embb[tok]
    const unsigned short* xp[4];
    #pragma unroll
    for (int rt = 0; rt < 4; ++rt) {
        const int row = rowBase + rt * 16 + col15;
        const int b = row >> 9, i = row & 511;
        const int tok = tokens[b * NNODES + 511 + i];
        xp[rt] = embb + (size_t)tok * HDIM + quad * 8;
    }

    // B pointers: gates {0,3,4}, Wx part of WTf = ks 16..23
    static const int GL[3] = {0, 3, 4};
    const short8v* bp[3];
    #pragma unroll
    for (int gi = 0; gi < 3; ++gi)
        bp[gi] = (const short8v*)WTf +
                 ((size_t)(GL[gi] * 16 + jtile * 4 + w) * 24 + 16) * 64 + lane;

    float4v acc[4][3];
    #pragma unroll
    for (int rt = 0; rt < 4; ++rt)
        #pragma unroll
        for (int gi = 0; gi < 3; ++gi)
            #pragma unroll
            for (int e = 0; e < 4; ++e) acc[rt][gi][e] = 0.0f;

    short8v abuf[2][4], bbuf[2][3];
    #pragma unroll
    for (int rt = 0; rt < 4; ++rt) abuf[0][rt] = *(const short8v*)xp[rt];
    #pragma unroll
    for (int gi = 0; gi < 3; ++gi) bbuf[0][gi] = bp[gi][0];

    #pragma unroll
    for (int ks = 0; ks < 8; ++ks) {
        const int cur = ks & 1, nxt = cur ^ 1;
        if (ks < 7) {
            #pragma unroll
            for (int rt = 0; rt < 4; ++rt)
                abuf[nxt][rt] = *(const short8v*)(xp[rt] + (ks + 1) * 32);
            #pragma unroll
            for (int gi = 0; gi < 3; ++gi) bbuf[nxt][gi] = bp[gi][(ks + 1) * 64];
        }
        #pragma unroll
        for (int rt = 0; rt < 4; ++rt)
            #pragma unroll
            for (int gi = 0; gi < 3; ++gi)
                acc[rt][gi] = __builtin_amdgcn_mfma_f32_16x16x32_bf16(
                    abuf[cur][rt], bbuf[cur][gi], acc[rt][gi], 0, 0, 0);
    }

    // Cell + writeback (C layout: col=lane&15, row=quad*4+reg)
    const int jl = w * 16 + col15;
    const int j  = jbase + jl;
    const float b_i = bias[j], b_o = bias[768 + j], b_u = bias[1024 + j];
    const int jchunk = jl >> 3, jpos = jl & 7;
    #pragma unroll
    for (int rt = 0; rt < 4; ++rt) {
        #pragma unroll
        for (int reg = 0; reg < 4; ++reg) {
            const int rr = rt * 16 + quad * 4 + reg;
            const float gi = acc[rt][0][reg] + b_i;
            const float go = acc[rt][1][reg] + b_o;
            const float gu = acc[rt][2][reg] + b_u;
            const float c = sigm(gi) * tanh_fast(gu);
            const float h = sigm(go) * tanh_fast(c);
            const int roff = ((jchunk + 2 * quad) & 7) * 8 + jpos;
            wb[rr * 64 + roff]        = f2bf(h);
            wb[4096 + rr * 64 + roff] = f2bf(c);
        }
    }
    __syncthreads();
    #pragma unroll
    for (int k = 0; k < 4; ++k) {
        const int c = tid + k * 256;                 // 0..1023
        const int arr = c >> 9, rr = (c >> 3) & 63, u = c & 7;
        const int ru = (u + 2 * ((rr >> 2) & 3)) & 7;
        const short8v v = *(const short8v*)(wb + (arr * 4096 + rr * 64 + ru * 8));
        unsigned short* dstp = (arr ? cdst : hdst) +
            (size_t)(rowBase + rr) * HDIM + jbase + u * 8;
        *(short8v*)dstp = v;
    }
}

// ---------------------------------------------------------------------------
// Inner level d (8..0): MFMA GEMM [hl|hr|x](Mx768) @ [Ul;Ur;Wx](768x1280) +
// LSTM cell.  Row id r = b*n + i; child rows of r are 2r, 2r+1 in the child
// slot (contiguous streams).  x = embb[tok] gathered from L2-resident 1 MB
// table (round-5 postmortem: the EWb gather's random 128B HBM traffic was the
// real limiter; EWb is gone).  No LDS in the K-loop; dist-1 register dbuf.
// ---------------------------------------------------------------------------
__global__ __launch_bounds__(256) void level_kernel(
    const unsigned short* __restrict__ WTf, const unsigned short* __restrict__ embb,
    const float* __restrict__ bias, const int* __restrict__ tokens,
    const unsigned short* __restrict__ hsrc, const unsigned short* __restrict__ csrc,
    unsigned short* __restrict__ hdst, unsigned short* __restrict__ cdst,
    float* __restrict__ out, const int d)
{
    const int n = 1 << d;

    __shared__ __align__(16) unsigned short cst[128 * 64];   // 16 KB child c (swizzled)
    __shared__ __align__(16) unsigned short wb[2 * 4096];    // 16 KB h/c writeback

    const int tid  = threadIdx.x;
    const int lane = tid & 63;
    const int w    = tid >> 6;
    const int quad = lane >> 4, col15 = lane & 15;
    const int jtile   = blockIdx.x;            // 0..3
    const int rowBase = blockIdx.y * 64;
    const int jbase   = jtile * 64;

    // ---- A pointers: child h rows 2r (left) / 2r+1 (right, +HDIM), x rows ----
    const unsigned short* chp[4];
    const unsigned short* xp[4];
    #pragma unroll
    for (int rt = 0; rt < 4; ++rt) {
        const int row = rowBase + rt * 16 + col15;
        const int b = row >> d, i = row & (n - 1);
        chp[rt] = hsrc + (size_t)(2 * row) * HDIM + quad * 8;
        const int tok = tokens[b * NNODES + (n - 1) + i];
        xp[rt] = embb + (size_t)tok * HDIM + quad * 8;
    }

    // ---- B pointers: gate g -> ng = g*16 + jtile*4 + w ----
    const short8v* bp[5];
    #pragma unroll
    for (int g = 0; g < 5; ++g)
        bp[g] = (const short8v*)WTf +
                ((size_t)(g * 16 + jtile * 4 + w) * 24) * 64 + lane;

    float4v acc[4][5];
    #pragma unroll
    for (int rt = 0; rt < 4; ++rt)
        #pragma unroll
        for (int g = 0; g < 5; ++g)
            #pragma unroll
            for (int e = 0; e < 4; ++e) acc[rt][g][e] = 0.0f;

    short8v abuf[2][4], bbuf[2][5];
    #pragma unroll
    for (int rt = 0; rt < 4; ++rt) abuf[0][rt] = *(const short8v*)chp[rt];
    #pragma unroll
    for (int g = 0; g < 5; ++g) bbuf[0][g] = bp[g][0];

    #pragma unroll
    for (int ks = 0; ks < KS_LVL; ++ks) {
        const int cur = ks & 1, nxt = cur ^ 1;
        if (ks < KS_LVL - 1) {
            const int kn = ks + 1;
            #pragma unroll
            for (int rt = 0; rt < 4; ++rt) {
                const unsigned short* p =
                    (kn < 8)  ? (chp[rt] + kn * 32)
                  : (kn < 16) ? (chp[rt] + HDIM + (kn - 8) * 32)
                              : (xp[rt] + (kn - 16) * 32);
                abuf[nxt][rt] = *(const short8v*)p;
            }
            #pragma unroll
            for (int g = 0; g < 5; ++g) bbuf[nxt][g] = bp[g][(size_t)kn * 64];
        }
        #pragma unroll
        for (int rt = 0; rt < 4; ++rt)
            #pragma unroll
            for (int g = 0; g < 5; ++g)
                acc[rt][g] = __builtin_amdgcn_mfma_f32_16x16x32_bf16(
                    abuf[cur][rt], bbuf[cur][g], acc[rt][g], 0, 0, 0);
    }

    // ---- Stage child c (rows 2*rowBase .. +128, contiguous stream) ----
    #pragma unroll
    for (int k = 0; k < 4; ++k) {
        const int c = tid + k * 256;
        const int rr = c >> 4, side = (c >> 3) & 1, u = c & 7;
        const short8v v = *(const short8v*)(csrc +
            (size_t)(2 * (rowBase + rr) + side) * HDIM + jbase + u * 8);
        const int ru = (u + 2 * ((rr >> 2) & 3)) & 7;
        *(short8v*)(cst + (rr * 128 + side * 64 + ru * 8)) = v;
    }
    __syncthreads();

    // ---- Cell math (C layout: col=lane&15, row=quad*4+reg) ----
    const int jl = w * 16 + col15;
    const int j  = jbase + jl;
    const float b_i  = bias[j],       b_fl = bias[256 + j], b_fr = bias[512 + j];
    const float b_o  = bias[768 + j], b_u  = bias[1024 + j];
    const int jchunk = jl >> 3, jpos = jl & 7;
    float hv[4][4], cv[4][4];
    #pragma unroll
    for (int rt = 0; rt < 4; ++rt) {
        #pragma unroll
        for (int reg = 0; reg < 4; ++reg) {
            const int rr = rt * 16 + quad * 4 + reg;
            const int roff = ((jchunk + 2 * quad) & 7) * 8 + jpos;  // (rr>>2)&3 == quad
            const float gi  = acc[rt][0][reg] + b_i;
            const float gfl = acc[rt][1][reg] + b_fl;
            const float gfr = acc[rt][2][reg] + b_fr;
            const float go  = acc[rt][3][reg] + b_o;
            const float gu  = acc[rt][4][reg] + b_u;
            const float cl  = bf2f(cst[rr * 128 +      roff]);
            const float cr  = bf2f(cst[rr * 128 + 64 + roff]);
            const float ii = sigm(gi), fl = sigm(gfl), fr = sigm(gfr), oo = sigm(go);
            const float uu = tanh_fast(gu);
            const float c = ii * uu + fl * cl + fr * cr;
            const float h = oo * tanh_fast(c);
            cv[rt][reg] = c; hv[rt][reg] = h;
            if (d == 0) out[(size_t)(rowBase + rr) * HDIM + j] = h;  // n==1 -> b=row
        }
    }
    __syncthreads();

    // ---- Writeback h/c via LDS -> coalesced 16B stores ----
    #pragma unroll
    for (int rt = 0; rt < 4; ++rt) {
        #pragma unroll
        for (int reg = 0; reg < 4; ++reg) {
            const int rr = rt * 16 + quad * 4 + reg;
            const int roff = ((jchunk + 2 * quad) & 7) * 8 + jpos;
            wb[rr * 64 + roff]        = f2bf(hv[rt][reg]);
            wb[4096 + rr * 64 + roff] = f2bf(cv[rt][reg]);
        }
    }
    __syncthreads();
    #pragma unroll
    for (int k = 0; k < 4; ++k) {
        const int c = tid + k * 256;                 // 0..1023
        const int arr = c >> 9, rr = (c >> 3) & 63, u = c & 7;
        const int ru = (u + 2 * ((rr >> 2) & 3)) & 7;
        const short8v v = *(const short8v*)(wb + (arr * 4096 + rr * 64 + ru * 8));
        unsigned short* dstp = (arr ? cdst : hdst) +
            (size_t)(rowBase + rr) * HDIM + jbase + u * 8;
        *(short8v*)dstp = v;
    }
}

// ---------------------------------------------------------------------------
extern "C" void kernel_launch(void* const* d_in, const int* in_sizes, int n_in,
                              void* d_out, int out_size, void* d_ws, size_t ws_size,
                              hipStream_t stream)
{
    const int*   tokens = (const int*)d_in[0];
    const float* emb    = (const float*)d_in[1];
    const float* Wx     = (const float*)d_in[2];
    const float* Ul     = (const float*)d_in[3];
    const float* Ur     = (const float*)d_in[4];
    const float* bias   = (const float*)d_in[5];
    float* out = (float*)d_out;

    // Workspace (bf16): embb 1.05 MB | WTf 1.97 MB | hA,cA 67.1 MB | hB,cB 33.6 MB
    // total ~103.7 MB
    const size_t EMB_ELEMS = (size_t)VOCAB * HDIM;
    const size_t WTF_ELEMS = (size_t)80 * 24 * 64 * 8;
    const size_t SLOT_A    = (size_t)512 * B_SZ * HDIM;   // leaf level rows
    const size_t SLOT_B    = (size_t)256 * B_SZ * HDIM;
    const size_t REQUIRED  = (EMB_ELEMS + WTF_ELEMS + 2 * (SLOT_A + SLOT_B)) * 2;
    if (ws_size < REQUIRED || d_ws == nullptr) return;    // clean fail, not a fault

    char* ws = (char*)d_ws;
    unsigned short* embb = (unsigned short*)ws;
    unsigned short* WTf  = embb + EMB_ELEMS;
    unsigned short* hA   = WTf + WTF_ELEMS;
    unsigned short* cA   = hA + SLOT_A;
    unsigned short* hB   = cA + SLOT_A;
    unsigned short* cB   = hB + SLOT_B;

    embb_kernel<<<dim3(256), 256, 0, stream>>>(emb, embb);
    prep_wtf<<<dim3(480), 256, 0, stream>>>(Ul, Ur, Wx, WTf);

    // Leaf level d=9 -> slot A (rows r = b*512 + i)
    leaf_kernel<<<dim3(4, 1024), 256, 0, stream>>>(WTf, embb, bias, tokens, hA, cA);

    // Levels d=8..0: even d reads A writes B, odd d reads B writes A
    for (int d = 8; d >= 0; --d) {
        const int M = B_SZ << d;
        const bool evenD = ((d & 1) == 0);
        const unsigned short* hs = evenD ? hA : hB;
        const unsigned short* cs = evenD ? cA : cB;
        unsigned short* hd = evenD ? hB : hA;
        unsigned short* cd = evenD ? cB : cA;
        level_kernel<<<dim3(4, M / 64), 256, 0, stream>>>(
            WTf, embb, bias, tokens, hs, cs, hd, cd, out, d);
    }
}